// Round 6
// baseline (222.696 us; speedup 1.0000x reference)
//
#include <hip/hip_runtime.h>

// 1 - alpha = (1 + exp(density+shift))^(-0.5) = rsqrt(u), u = 1 + exp(x).
// w = T_excl * alpha = T_incl * (u*a - 1).

__device__ __forceinline__ float fast_sigmoid(float x) {
    return __builtin_amdgcn_rcpf(1.0f + __expf(-x));
}

// ---- DPP wave64 scans ------------------------------------------------------
#define DPP_ADD(x, ctrl, rmask)                                               \
    do {                                                                      \
        int _s = __builtin_amdgcn_update_dpp(0, __float_as_int(x), (ctrl),    \
                                             (rmask), 0xf, true);             \
        (x) += __int_as_float(_s);                                            \
    } while (0)

#define DPP_MUL(x, ctrl, rmask)                                               \
    do {                                                                      \
        int _s = __builtin_amdgcn_update_dpp(0x3f800000, __float_as_int(x),   \
                                             (ctrl), (rmask), 0xf, false);    \
        (x) *= __int_as_float(_s);                                            \
    } while (0)

__device__ __forceinline__ float wave_scan_add(float x) {
    DPP_ADD(x, 0x111, 0xf);  // row_shr:1
    DPP_ADD(x, 0x112, 0xf);  // row_shr:2
    DPP_ADD(x, 0x114, 0xf);  // row_shr:4
    DPP_ADD(x, 0x118, 0xf);  // row_shr:8
    DPP_ADD(x, 0x142, 0xa);  // row_bcast:15 -> rows 1,3
    DPP_ADD(x, 0x143, 0xc);  // row_bcast:31 -> rows 2,3
    return x;
}

__device__ __forceinline__ float wave_scan_mul(float x) {
    DPP_MUL(x, 0x111, 0xf);
    DPP_MUL(x, 0x112, 0xf);
    DPP_MUL(x, 0x114, 0xf);
    DPP_MUL(x, 0x118, 0xf);
    DPP_MUL(x, 0x142, 0xa);
    DPP_MUL(x, 0x143, 0xc);
    return x;
}

__device__ __forceinline__ float bcast_lane63(float x) {
    return __int_as_float(__builtin_amdgcn_readlane(__float_as_int(x), 63));
}

struct f3 { float x, y, z; };   // packed 12B -> global_load_dwordx3-able

// ---- Pass 1: segment starts; prev via shuffle (single read of ray_id) ------
__global__ __launch_bounds__(256) void seg_starts4_kernel(
    const int4* __restrict__ ray4, int M4, int M, int N,
    const int* __restrict__ ray_id, int* __restrict__ starts)
{
    const int i = blockIdx.x * blockDim.x + threadIdx.x;
    if (i >= M4) return;
    const int4 v = ray4[i];
    const int t = threadIdx.x & 63;
    int prev = __shfl_up(v.w, 1);            // lane t-1's last element
    if (t == 0)                               // wave boundary: one load per wave
        prev = (i == 0) ? -1 : ray_id[4 * i - 1];
    const int base = 4 * i;
    for (int r = prev + 1; r <= v.x; ++r) starts[r] = base;
    for (int r = v.x + 1;  r <= v.y; ++r) starts[r] = base + 1;
    for (int r = v.y + 1;  r <= v.z; ++r) starts[r] = base + 2;
    for (int r = v.z + 1;  r <= v.w; ++r) starts[r] = base + 3;
    if (i == M4 - 1) {
        int last = v.w;
        for (int j = 4 * M4; j < M; ++j) {   // scalar tail (M%4)
            const int cur = ray_id[j];
            for (int r = last + 1; r <= cur; ++r) starts[r] = j;
            last = cur;
        }
        for (int r = last + 1; r <= N; ++r) starts[r] = M;
    }
}

// ---- Pass 2: RPW rays per wave; all chunk-0 loads issued up front ----------
#define RPW 8

__global__ __launch_bounds__(256) void favor_render_kernel(
    const float* __restrict__ density,
    const float* __restrict__ rgb_feat,   // [M,3]
    const float* __restrict__ shift,      // [1]
    const int*   __restrict__ starts,     // [N+1]
    int M, int N,
    float* __restrict__ weights,          // [M]
    float* __restrict__ alphainv_last,    // [N]
    float* __restrict__ out3)             // [N,3]
{
    const int wave = (blockIdx.x * blockDim.x + threadIdx.x) >> 6;
    const int t    = threadIdx.x & 63;
    const int r0   = wave * RPW;
    if (r0 >= N) return;

    const f3* __restrict__ rgb3 = (const f3*)rgb_feat;

    // Bounds for all RPW rays: one coalesced load, broadcast to SGPRs.
    const int bv = starts[min(r0 + t, N)];
    int s[RPW + 1];
    #pragma unroll
    for (int k = 0; k <= RPW; ++k)
        s[k] = __builtin_amdgcn_readlane(bv, k);

    const float sh = shift[0];

    // Prefetch chunk-0 for ALL rays (8 density + 8 dwordx3 loads in flight).
    float pd[RPW];
    f3    pc[RPW];
    #pragma unroll
    for (int j = 0; j < RPW; ++j) {
        const int c = max(min(s[j] + t, s[j + 1] - 1), 0);
        pd[j] = density[c];
        pc[j] = rgb3[c];
    }

    #pragma unroll
    for (int j = 0; j < RPW; ++j) {
        const int ray = r0 + j;
        if (ray >= N) continue;
        const int st = s[j], en = s[j + 1];

        float carryT = 1.0f;
        float a0 = 0.0f, a1 = 0.0f, a2 = 0.0f;

        // chunk 0 (prefetched)
        {
            const bool valid = (st + t) < en;
            const float u = 1.0f + __expf(pd[j] + sh);
            const float a = __builtin_amdgcn_rsqf(u);      // 1 - alpha
            const float m = valid ? a : 1.0f;
            const float S = wave_scan_mul(m);              // inclusive product
            const float tot = bcast_lane63(S);
            const float w = S * (u * a - 1.0f);            // T_excl * alpha
            if (valid) {
                weights[st + t] = w;
                a0 = w * fast_sigmoid(pc[j].x);
                a1 = w * fast_sigmoid(pc[j].y);
                a2 = w * fast_sigmoid(pc[j].z);
            }
            carryT = tot;
        }

        // remaining chunks (~47% of rays have one)
        for (int base = st + 64; base < en; base += 64) {
            const int i = base + t;
            const bool valid = i < en;
            const int c = min(i, en - 1);
            const float d = density[c];
            const f3 cc = rgb3[c];
            const float u = 1.0f + __expf(d + sh);
            const float a = __builtin_amdgcn_rsqf(u);
            const float m = valid ? a : 1.0f;
            const float S = wave_scan_mul(m);
            const float tot = bcast_lane63(S);
            const float w = carryT * S * (u * a - 1.0f);
            if (valid) {
                weights[i] = w;
                a0 += w * fast_sigmoid(cc.x);
                a1 += w * fast_sigmoid(cc.y);
                a2 += w * fast_sigmoid(cc.z);
            }
            carryT *= tot;
        }

        // per-ray epilogue (three independent DPP reduction chains)
        const float t0 = bcast_lane63(wave_scan_add(a0));
        const float t1 = bcast_lane63(wave_scan_add(a1));
        const float t2 = bcast_lane63(wave_scan_add(a2));
        if (t == 0) {
            alphainv_last[ray] = carryT;
            out3[3 * ray + 0] = t0 + carryT;
            out3[3 * ray + 1] = t1 + carryT;
            out3[3 * ray + 2] = t2 + carryT;
        }
    }
}

extern "C" void kernel_launch(void* const* d_in, const int* in_sizes, int n_in,
                              void* d_out, int out_size, void* d_ws, size_t ws_size,
                              hipStream_t stream) {
    const float* density  = (const float*)d_in[0];
    const float* rgb_feat = (const float*)d_in[1];
    const float* shift    = (const float*)d_in[2];
    const int*   ray_id   = (const int*)d_in[3];

    const int M = in_sizes[0];
    const int N = (out_size - M) / 4;   // out_size = M + N + 3N

    float* weights       = (float*)d_out;
    float* alphainv_last = weights + M;
    float* out3          = alphainv_last + N;

    const int block = 256;
    int* starts = (int*)d_ws;

    const int M4 = M >> 2;
    const int grid_starts = (M4 + block - 1) / block;
    seg_starts4_kernel<<<grid_starts, block, 0, stream>>>(
        (const int4*)ray_id, M4, M, N, ray_id, starts);

    const int n_waves = (N + RPW - 1) / RPW;
    const int grid_render = (n_waves * 64 + block - 1) / block;
    favor_render_kernel<<<grid_render, block, 0, stream>>>(
        density, rgb_feat, shift, starts, M, N,
        weights, alphainv_last, out3);
}